// Round 5
// baseline (223.787 us; speedup 1.0000x reference)
//
#include <hip/hip_runtime.h>

// Problem constants (from reference)
#define BATCH 4
#define POINT_NUM 50000
#define NPTS (BATCH * POINT_NUM)   // 200000
#define NVOX 150000
#define FEAT 256

// Native vector type for __builtin_nontemporal_load (HIP's float4 is a
// class type the builtin rejects).
typedef float vfloat4 __attribute__((ext_vector_type(4)));

// k1: mark voxels referenced by any point (benign races; all write 1).
// No zeroing pass needed — d_ws is poisoned 0xAA by the harness, so
// unreferenced bytes are !=1. A stale byte equal to 1 only causes extra
// (harmless) projection work; referenced voxels are ALWAYS marked, so the
// gather never reads an uncomputed score. Correct for any initial ws state.
__global__ __launch_bounds__(256) void mark_kernel(
    const int* __restrict__ idx, unsigned char* __restrict__ mask) {
    const int p = blockIdx.x * blockDim.x + threadIdx.x;
    if (p < NPTS) mask[idx[p]] = 1;
}

// k2: project referenced voxel rows through the 2x256 linear layer.
// One wave per row (64 lanes x float4 = 1 KB coalesced read). Unreferenced
// rows are skipped via a wave-uniform branch (~26% traffic saved for
// uniform random idx). Feature reads are nontemporal (read-once stream).
__global__ __launch_bounds__(256) void project_kernel(
    const float* __restrict__ feat,   // [NVOX, FEAT]
    const float* __restrict__ w,      // [2, FEAT]
    const float* __restrict__ bias,   // [2]
    const unsigned char* __restrict__ mask,
    float2* __restrict__ s)           // [NVOX] interleaved (s0,s1)
{
    const int wave = (blockIdx.x * blockDim.x + threadIdx.x) >> 6;
    const int lane = threadIdx.x & 63;
    if (wave >= NVOX) return;
    if (mask[wave] != 1) return;      // wave-uniform: whole wave skips

    const float4 w0 = ((const float4*)(w))[lane];
    const float4 w1 = ((const float4*)(w + FEAT))[lane];
    const vfloat4* frow = (const vfloat4*)(feat + (size_t)wave * FEAT);
    const vfloat4 f = __builtin_nontemporal_load(frow + lane);

    float a = f.x * w0.x + f.y * w0.y + f.z * w0.z + f.w * w0.w;
    float b = f.x * w1.x + f.y * w1.y + f.z * w1.z + f.w * w1.w;

    #pragma unroll
    for (int off = 32; off > 0; off >>= 1) {
        a += __shfl_down(a, off, 64);
        b += __shfl_down(b, off, 64);
    }

    if (lane == 0) s[wave] = make_float2(a + bias[0], b + bias[1]);
}

// k3: per-point gather — one 8B random read from the 1.2 MB score table
// (L2-resident), two coalesced 4B writes.
__global__ __launch_bounds__(256) void gather_kernel(
    const int* __restrict__ idx,
    const float2* __restrict__ s,
    float* __restrict__ out)          // [2, NPTS]
{
    const int p = blockIdx.x * blockDim.x + threadIdx.x;
    if (p >= NPTS) return;
    const float2 v = s[idx[p]];
    out[p]        = v.x;
    out[NPTS + p] = v.y;
}

extern "C" void kernel_launch(void* const* d_in, const int* in_sizes, int n_in,
                              void* d_out, int out_size, void* d_ws, size_t ws_size,
                              hipStream_t stream) {
    const float* feat = (const float*)d_in[0];
    const int*   idx  = (const int*)d_in[1];
    const float* w    = (const float*)d_in[2];
    const float* bias = (const float*)d_in[3];
    float* out = (float*)d_out;

    float2* s = (float2*)d_ws;                        // [NVOX] = 1.2 MB
    unsigned char* mask = (unsigned char*)(s + NVOX); // [NVOX] bytes

    mark_kernel<<<(NPTS + 255) / 256, 256, 0, stream>>>(idx, mask);

    const int blocks1 = (NVOX * 64 + 255) / 256;      // one wave per voxel
    project_kernel<<<blocks1, 256, 0, stream>>>(feat, w, bias, mask, s);

    gather_kernel<<<(NPTS + 255) / 256, 256, 0, stream>>>(idx, s, out);
}

// Round 6
// 217.374 us; speedup vs baseline: 1.0295x; 1.0295x over previous
//
#include <hip/hip_runtime.h>

// Problem constants (from reference)
#define BATCH 4
#define POINT_NUM 50000
#define NPTS (BATCH * POINT_NUM)   // 200000
#define NVOX 150000
#define FEAT 256

// Native vector type for __builtin_nontemporal_load (HIP's float4 is a
// class type the builtin rejects).
typedef float vfloat4 __attribute__((ext_vector_type(4)));

// k1: project ALL voxel rows through the 2x256 linear layer.
// One wave per row: 64 lanes x float4 = 1 KB fully-coalesced sequential
// read -> streams at HBM BW. Dense stream beats mask-skipping (R3/R5:
// sparse holes lose DRAM row locality + extra dispatch cost).
// Feature reads are nontemporal (read-once; keep L2 for idx/score table).
__global__ __launch_bounds__(256) void project_kernel(
    const float* __restrict__ feat,   // [NVOX, FEAT]
    const float* __restrict__ w,      // [2, FEAT]
    const float* __restrict__ bias,   // [2]
    float2* __restrict__ s)           // [NVOX] interleaved (s0,s1)
{
    const int wave = (blockIdx.x * blockDim.x + threadIdx.x) >> 6;
    const int lane = threadIdx.x & 63;
    if (wave >= NVOX) return;

    const float4 w0 = ((const float4*)(w))[lane];
    const float4 w1 = ((const float4*)(w + FEAT))[lane];
    const vfloat4* frow = (const vfloat4*)(feat + (size_t)wave * FEAT);
    const vfloat4 f = __builtin_nontemporal_load(frow + lane);

    float a = f.x * w0.x + f.y * w0.y + f.z * w0.z + f.w * w0.w;
    float b = f.x * w1.x + f.y * w1.y + f.z * w1.z + f.w * w1.w;

    #pragma unroll
    for (int off = 32; off > 0; off >>= 1) {
        a += __shfl_down(a, off, 64);
        b += __shfl_down(b, off, 64);
    }

    if (lane == 0) s[wave] = make_float2(a + bias[0], b + bias[1]);
}

// k2: per-point gather — one 8B random read from the 1.2 MB score table
// (L2-resident), two coalesced nontemporal 4B writes.
__global__ __launch_bounds__(256) void gather_kernel(
    const int* __restrict__ idx,
    const float2* __restrict__ s,
    float* __restrict__ out)          // [2, NPTS]
{
    const int p = blockIdx.x * blockDim.x + threadIdx.x;
    if (p >= NPTS) return;
    const float2 v = s[idx[p]];
    __builtin_nontemporal_store(v.x, out + p);
    __builtin_nontemporal_store(v.y, out + NPTS + p);
}

extern "C" void kernel_launch(void* const* d_in, const int* in_sizes, int n_in,
                              void* d_out, int out_size, void* d_ws, size_t ws_size,
                              hipStream_t stream) {
    const float* feat = (const float*)d_in[0];
    const int*   idx  = (const int*)d_in[1];
    const float* w    = (const float*)d_in[2];
    const float* bias = (const float*)d_in[3];
    float* out = (float*)d_out;

    float2* s = (float2*)d_ws;                   // [NVOX] = 1.2 MB scratch

    const int blocks1 = (NVOX * 64 + 255) / 256; // one wave per voxel
    project_kernel<<<blocks1, 256, 0, stream>>>(feat, w, bias, s);

    gather_kernel<<<(NPTS + 255) / 256, 256, 0, stream>>>(idx, s, out);
}